// Round 8
// baseline (471.735 us; speedup 1.0000x reference)
//
#include <hip/hip_runtime.h>

#define NN 50000
#define NE 800000
#define NB ((NN + 255) / 256)   // 196 scan blocks

typedef unsigned int uint32;
typedef unsigned short ushort16;

__device__ __forceinline__ ushort16 f2bf(float f) {
    uint32 u = __float_as_uint(f);
    u += 0x7fff + ((u >> 16) & 1);      // round-to-nearest-even
    return (ushort16)(u >> 16);
}
__device__ __forceinline__ float bf2f(ushort16 h) {
    return __uint_as_float(((uint32)h) << 16);
}
__device__ __forceinline__ float bf_lo(uint32 u) {
    return __uint_as_float(u << 16);
}
__device__ __forceinline__ float bf_hi(uint32 u) {
    return __uint_as_float(u & 0xffff0000u);
}

// ---------------------------------------------------------------------------
// k_lin12: a = x@W1 + b1 (fp32 + bf16 copy) ; skip = x@W2 + b2
// ---------------------------------------------------------------------------
__global__ __launch_bounds__(256) void k_lin12(
    const float* __restrict__ x,
    const float* __restrict__ w1, const float* __restrict__ b1,
    const float* __restrict__ w2, const float* __restrict__ b2,
    float* __restrict__ a, ushort16* __restrict__ ab, float* __restrict__ skip)
{
    __shared__ float xs[32][128];
    const int tid = threadIdx.x;
    const int row0 = blockIdx.x * 32;
    for (int i = tid; i < 32 * 128; i += 256) {
        const int gr = row0 + (i >> 7);
        ((float*)xs)[i] = (gr < NN) ? x[gr * 128 + (i & 127)] : 0.f;
    }
    __syncthreads();

    const int col = tid & 63;
    const int g = tid >> 6;
    float acc1[8], acc2[8];
#pragma unroll
    for (int r = 0; r < 8; ++r) { acc1[r] = 0.f; acc2[r] = 0.f; }

#pragma unroll 2
    for (int k0 = 0; k0 < 128; k0 += 4) {
        float wr1[4], wr2[4];
#pragma unroll
        for (int kk = 0; kk < 4; ++kk) {
            wr1[kk] = w1[(k0 + kk) * 64 + col];
            wr2[kk] = w2[(k0 + kk) * 64 + col];
        }
#pragma unroll
        for (int r = 0; r < 8; ++r) {
            const float4 xv = *(const float4*)&xs[g * 8 + r][k0];
            acc1[r] += xv.x * wr1[0] + xv.y * wr1[1] + xv.z * wr1[2] + xv.w * wr1[3];
            acc2[r] += xv.x * wr2[0] + xv.y * wr2[1] + xv.z * wr2[2] + xv.w * wr2[3];
        }
    }

    const float bv1 = b1[col];
    const float bv2 = b2[col];
#pragma unroll
    for (int r = 0; r < 8; ++r) {
        const int gr = row0 + g * 8 + r;
        if (gr < NN) {
            const float v1 = acc1[r] + bv1;
            a[gr * 64 + col]    = v1;
            ab[gr * 64 + col]   = f2bf(v1);
            skip[gr * 64 + col] = acc2[r] + bv2;
        }
    }
}

// ---------------------------------------------------------------------------
// k_t: t[n,h] = a[n,:] @ u[:,h]   ([NN,64]@[64,4]) — one thread per (n,h)
// ---------------------------------------------------------------------------
__global__ __launch_bounds__(256) void k_t(
    const float* __restrict__ a, const float* __restrict__ u,
    float* __restrict__ t)
{
    const int gid = blockIdx.x * 256 + threadIdx.x;
    if (gid >= NN * 4) return;
    const int n = gid >> 2, h = gid & 3;
    const float* ar = a + n * 64;
    float s = 0.f;
#pragma unroll 4
    for (int k = 0; k < 64; ++k) s += ar[k] * u[k * 4 + h];
    t[gid] = s;
}

// ---------------------------------------------------------------------------
// k_lin3: out = h@W + b   ([NN,64]@[64,64])
// ---------------------------------------------------------------------------
__global__ __launch_bounds__(256) void k_lin3(
    const float* __restrict__ h,
    const float* __restrict__ w, const float* __restrict__ b,
    float* __restrict__ out)
{
    __shared__ float hs[32][64];
    const int tid = threadIdx.x;
    const int row0 = blockIdx.x * 32;
    for (int i = tid; i < 32 * 64; i += 256) {
        const int gr = row0 + (i >> 6);
        ((float*)hs)[i] = (gr < NN) ? h[gr * 64 + (i & 63)] : 0.f;
    }
    __syncthreads();

    const int col = tid & 63;
    const int g = tid >> 6;
    float acc[8];
#pragma unroll
    for (int r = 0; r < 8; ++r) acc[r] = 0.f;

#pragma unroll 2
    for (int k0 = 0; k0 < 64; k0 += 4) {
        float wr[4];
#pragma unroll
        for (int kk = 0; kk < 4; ++kk)
            wr[kk] = w[(k0 + kk) * 64 + col];
#pragma unroll
        for (int r = 0; r < 8; ++r) {
            const float4 xv = *(const float4*)&hs[g * 8 + r][k0];
            acc[r] += xv.x * wr[0] + xv.y * wr[1] + xv.z * wr[2] + xv.w * wr[3];
        }
    }

    const float bv = b[col];
#pragma unroll
    for (int r = 0; r < 8; ++r) {
        const int gr = row0 + g * 8 + r;
        if (gr < NN) out[gr * 64 + col] = acc[r] + bv;
    }
}

// ---------------------------------------------------------------------------
// CSR build: histogram -> hierarchical scan -> scatter (src only, 4B)
// ---------------------------------------------------------------------------
__global__ __launch_bounds__(256) void k_hist(const int* __restrict__ ei,
                                              int* __restrict__ deg)
{
    const int i = blockIdx.x * 256 + threadIdx.x;
    if (i < NE) atomicAdd(&deg[ei[NE + i]], 1);
}

__global__ __launch_bounds__(256) void k_blocksum(const int* __restrict__ deg,
                                                  int* __restrict__ bsum)
{
    __shared__ int red[256];
    const int t = threadIdx.x;
    const int i = blockIdx.x * 256 + t;
    red[t] = (i < NN) ? deg[i] : 0;
    __syncthreads();
    for (int off = 128; off > 0; off >>= 1) {
        if (t < off) red[t] += red[t + off];
        __syncthreads();
    }
    if (t == 0) bsum[blockIdx.x] = red[0];
}

__global__ __launch_bounds__(256) void k_scanb(int* __restrict__ bsum)
{
    __shared__ int s[256];
    const int t = threadIdx.x;
    s[t] = (t < NB) ? bsum[t] : 0;
    __syncthreads();
    for (int off = 1; off < 256; off <<= 1) {
        const int v = (t >= off) ? s[t - off] : 0;
        __syncthreads();
        s[t] += v;
        __syncthreads();
    }
    if (t < NB) bsum[t] = (t == 0) ? 0 : s[t - 1];
}

__global__ __launch_bounds__(256) void k_scanfin(const int* __restrict__ deg,
                                                 const int* __restrict__ bsum,
                                                 int* __restrict__ row_ptr,
                                                 int* __restrict__ fill)
{
    __shared__ int s[256];
    const int t = threadIdx.x;
    const int i = blockIdx.x * 256 + t;
    const int v = (i < NN) ? deg[i] : 0;
    s[t] = v;
    __syncthreads();
    for (int off = 1; off < 256; off <<= 1) {
        const int u = (t >= off) ? s[t - off] : 0;
        __syncthreads();
        s[t] += u;
        __syncthreads();
    }
    const int excl = s[t] - v + bsum[blockIdx.x];
    if (i < NN) { row_ptr[i] = excl; fill[i] = excl; }
    if (i == NN - 1) row_ptr[NN] = excl + v;
}

__global__ __launch_bounds__(256) void k_scatter(const int* __restrict__ ei,
                                                 int* __restrict__ fill,
                                                 int* __restrict__ ssrc)
{
    const int i = blockIdx.x * 256 + threadIdx.x;
    if (i >= NE) return;
    const int src = ei[i];
    const int dst = ei[NE + i];
    const int pos = atomicAdd(&fill[dst], 1);
    ssrc[pos] = src;
}

// ---------------------------------------------------------------------------
// k_agg: one wave per dst node, lane = input-dim f. Aggregates INPUTS per
// head (z_h[f] = sum_e q_eh * a_bf16[src_e][f]) — 128 B/edge gather instead
// of the old 512 B y-row. Softmax computed in parallel per 64-edge chunk
// (lane i does edge i), broadcast via shfl. Writes zcat[node][f*4+h] bf16
// as one coalesced uint2/lane. Mean folded into q. No bias/skip here.
// ---------------------------------------------------------------------------
__global__ __launch_bounds__(256) void k_agg(
    const int* __restrict__ row_ptr, const int* __restrict__ ssrc,
    const float* __restrict__ t, const ushort16* __restrict__ ab,
    const float* __restrict__ c, uint2* __restrict__ zcat)
{
    const int lane = threadIdx.x & 63;
    const int node = (blockIdx.x * 256 + threadIdx.x) >> 6;
    if (node >= NN) return;

    const int r0 = row_ptr[node];
    const int r1 = row_ptr[node + 1];
    const int deg = r1 - r0;
    const float invdeg = (deg > 0) ? 1.f / (float)deg : 0.f;

    const float4 tc = *(const float4*)c;
    const float4 td = ((const float4*)t)[node];

    float z0 = 0.f, z1 = 0.f, z2 = 0.f, z3 = 0.f;
    for (int base = r0; base < r1; base += 64) {
        const int m = min(64, r1 - base);

        // --- phase 1: lane i computes softmax for edge base+i ---
        int src = 0;
        float q0 = 0.f, q1 = 0.f, q2 = 0.f, q3 = 0.f;
        if (lane < m) {
            src = ssrc[base + lane];
            const float4 ts = ((const float4*)t)[src];
            const float l0 = ts.x - td.x + tc.x;
            const float l1 = ts.y - td.y + tc.y;
            const float l2 = ts.z - td.z + tc.z;
            const float l3 = ts.w - td.w + tc.w;
            const float mx = fmaxf(fmaxf(l0, l1), fmaxf(l2, l3));
            const float e0 = __expf(l0 - mx);
            const float e1 = __expf(l1 - mx);
            const float e2 = __expf(l2 - mx);
            const float e3 = __expf(l3 - mx);
            const float s = invdeg / (e0 + e1 + e2 + e3);
            q0 = e0 * s; q1 = e1 * s; q2 = e2 * s; q3 = e3 * s;
        }

        // --- phase 2: accumulate a[src] per head, q/src via shfl ---
        int e = 0;
        for (; e + 3 < m; e += 4) {
#pragma unroll
            for (int k = 0; k < 4; ++k) {
                const int se = __shfl(src, e + k, 64);
                const float a0 = __shfl(q0, e + k, 64);
                const float a1 = __shfl(q1, e + k, 64);
                const float a2 = __shfl(q2, e + k, 64);
                const float a3 = __shfl(q3, e + k, 64);
                const float av = bf2f(ab[se * 64 + lane]);
                z0 += a0 * av; z1 += a1 * av; z2 += a2 * av; z3 += a3 * av;
            }
        }
        for (; e < m; ++e) {
            const int se = __shfl(src, e, 64);
            const float a0 = __shfl(q0, e, 64);
            const float a1 = __shfl(q1, e, 64);
            const float a2 = __shfl(q2, e, 64);
            const float a3 = __shfl(q3, e, 64);
            const float av = bf2f(ab[se * 64 + lane]);
            z0 += a0 * av; z1 += a1 * av; z2 += a2 * av; z3 += a3 * av;
        }
    }

    uint2 pk;
    pk.x = (uint32)f2bf(z0) | ((uint32)f2bf(z1) << 16);
    pk.y = (uint32)f2bf(z2) | ((uint32)f2bf(z3) << 16);
    zcat[node * 64 + lane] = pk;   // zcat[node][f*4+h], coalesced 512B/wave
}

// ---------------------------------------------------------------------------
// k_post: out = relu(zcat @ Wp + bias + skip), plus bf16 copy for next layer.
// zcat[n, idx] with idx=f*4+h; Wp[idx][col] = w[(idx>>2)*256 + (idx&3)*64 + col].
// k_lin3-style: 32 rows/block staged in LDS (bf16, 16 KB), K=256 chunked by 8.
// ---------------------------------------------------------------------------
__global__ __launch_bounds__(256) void k_post(
    const ushort16* __restrict__ zcat, const float* __restrict__ w,
    const float* __restrict__ bias, const float* __restrict__ skip,
    float* __restrict__ out, ushort16* __restrict__ outb)
{
    __shared__ ushort16 zs[32][256];
    const int tid = threadIdx.x;
    const int row0 = blockIdx.x * 32;
    // stage 32 rows x 512B = 1024 uint4
    for (int i = tid; i < 1024; i += 256) {
        const int r = i >> 5, cc = i & 31;
        const int gr = row0 + r;
        uint4 v = make_uint4(0, 0, 0, 0);
        if (gr < NN) v = ((const uint4*)zcat)[(size_t)gr * 32 + cc];
        *(uint4*)&zs[r][cc * 8] = v;
    }
    __syncthreads();

    const int col = tid & 63;
    const int g = tid >> 6;
    float acc[8];
#pragma unroll
    for (int r = 0; r < 8; ++r) acc[r] = 0.f;

    for (int k0 = 0; k0 < 256; k0 += 8) {
        float wr[8];
#pragma unroll
        for (int kk = 0; kk < 8; ++kk) {
            const int idx = k0 + kk;
            wr[kk] = w[(idx >> 2) * 256 + (idx & 3) * 64 + col];
        }
#pragma unroll
        for (int r = 0; r < 8; ++r) {
            const uint4 zv = *(const uint4*)&zs[g * 8 + r][k0]; // broadcast
            acc[r] += bf_lo(zv.x) * wr[0] + bf_hi(zv.x) * wr[1]
                    + bf_lo(zv.y) * wr[2] + bf_hi(zv.y) * wr[3]
                    + bf_lo(zv.z) * wr[4] + bf_hi(zv.z) * wr[5]
                    + bf_lo(zv.w) * wr[6] + bf_hi(zv.w) * wr[7];
        }
    }

    const float bv = bias[col];
#pragma unroll
    for (int r = 0; r < 8; ++r) {
        const int gr = row0 + g * 8 + r;
        if (gr < NN) {
            const float v = fmaxf(acc[r] + bv + skip[gr * 64 + col], 0.f);
            out[gr * 64 + col]  = v;
            outb[gr * 64 + col] = f2bf(v);
        }
    }
}

extern "C" void kernel_launch(void* const* d_in, const int* in_sizes, int n_in,
                              void* d_out, int out_size, void* d_ws, size_t ws_size,
                              hipStream_t stream) {
    const float* x       = (const float*)d_in[0];
    const int*   ei      = (const int*)d_in[1];   // [2, NE] int32
    const float* lin1_w  = (const float*)d_in[2];
    const float* lin1_b  = (const float*)d_in[3];
    const float* lin2_w  = (const float*)d_in[4];
    const float* lin2_b  = (const float*)d_in[5];
    const float* lin3_w  = (const float*)d_in[6];
    const float* lin3_b  = (const float*)d_in[7];
    const float* conv1_w = (const float*)d_in[8];
    const float* conv1_u = (const float*)d_in[9];
    const float* conv1_c = (const float*)d_in[10];
    const float* conv1_bias = (const float*)d_in[11];
    const float* conv2_w = (const float*)d_in[12];
    const float* conv2_u = (const float*)d_in[13];
    const float* conv2_c = (const float*)d_in[14];
    const float* conv2_bias = (const float*)d_in[15];
    float* out = (float*)d_out;

    // workspace layout (~62 MB, 16B-aligned sections)
    char* p = (char*)d_ws;
    float* a      = (float*)p;           p += (size_t)NN * 64 * 4;   // fp32 a / h
    float* skip   = (float*)p;           p += (size_t)NN * 64 * 4;
    float* tt     = (float*)p;           p += (size_t)NN * 4 * 4;
    ushort16* ab  = (ushort16*)p;        p += (size_t)NN * 64 * 2;   // bf16 a / h
    ushort16* zc  = (ushort16*)p;        p += (size_t)NN * 256 * 2;  // bf16 z
    int* ssrc     = (int*)p;             p += (size_t)NE * 4;
    int* deg      = (int*)p;             p += (size_t)NN * 4;
    int* row_ptr  = (int*)p;             p += (size_t)(NN + 1) * 4;
    int* fill     = (int*)p;             p += (size_t)NN * 4;
    int* bsum     = (int*)p;

    // ---- CSR build (edge_index identical for both layers) ----
    hipMemsetAsync(deg, 0, (size_t)NN * sizeof(int), stream);
    k_hist<<<(NE + 255) / 256, 256, 0, stream>>>(ei, deg);
    k_blocksum<<<NB, 256, 0, stream>>>(deg, bsum);
    k_scanb<<<1, 256, 0, stream>>>(bsum);
    k_scanfin<<<NB, 256, 0, stream>>>(deg, bsum, row_ptr, fill);
    k_scatter<<<(NE + 255) / 256, 256, 0, stream>>>(ei, fill, ssrc);

    // ---- layer 1 ----
    k_lin12<<<(NN + 31) / 32, 256, 0, stream>>>(x, lin1_w, lin1_b, lin2_w, lin2_b,
                                                a, ab, skip);
    k_t<<<(NN * 4 + 255) / 256, 256, 0, stream>>>(a, conv1_u, tt);
    k_agg<<<(NN + 3) / 4, 256, 0, stream>>>(row_ptr, ssrc, tt, ab, conv1_c, (uint2*)zc);
    k_post<<<(NN + 31) / 32, 256, 0, stream>>>(zc, conv1_w, conv1_bias, skip, a, ab);

    // ---- layer 2 ----
    k_t<<<(NN * 4 + 255) / 256, 256, 0, stream>>>(a, conv2_u, tt);
    k_lin3<<<(NN + 31) / 32, 256, 0, stream>>>(a, lin3_w, lin3_b, skip);
    k_agg<<<(NN + 3) / 4, 256, 0, stream>>>(row_ptr, ssrc, tt, ab, conv2_c, (uint2*)zc);
    k_post<<<(NN + 31) / 32, 256, 0, stream>>>(zc, conv2_w, conv2_bias, skip, out, ab);
}

// Round 9
// 465.783 us; speedup vs baseline: 1.0128x; 1.0128x over previous
//
#include <hip/hip_runtime.h>

#define NN 50000
#define NE 800000
#define NB ((NN + 255) / 256)   // 196 scan blocks

typedef unsigned int uint32;
typedef unsigned short ushort16;

__device__ __forceinline__ ushort16 f2bf(float f) {
    uint32 u = __float_as_uint(f);
    u += 0x7fff + ((u >> 16) & 1);      // round-to-nearest-even
    return (ushort16)(u >> 16);
}
__device__ __forceinline__ float bf2f(ushort16 h) {
    return __uint_as_float(((uint32)h) << 16);
}

// ---------------------------------------------------------------------------
// k_lin12: a = x@W1 + b1 (fp32 + bf16 copy) ; skip = x@W2 + b2
// ---------------------------------------------------------------------------
__global__ __launch_bounds__(256) void k_lin12(
    const float* __restrict__ x,
    const float* __restrict__ w1, const float* __restrict__ b1,
    const float* __restrict__ w2, const float* __restrict__ b2,
    float* __restrict__ a, ushort16* __restrict__ ab, float* __restrict__ skip)
{
    __shared__ float xs[32][128];
    const int tid = threadIdx.x;
    const int row0 = blockIdx.x * 32;
    for (int i = tid; i < 32 * 128; i += 256) {
        const int gr = row0 + (i >> 7);
        ((float*)xs)[i] = (gr < NN) ? x[gr * 128 + (i & 127)] : 0.f;
    }
    __syncthreads();

    const int col = tid & 63;
    const int g = tid >> 6;
    float acc1[8], acc2[8];
#pragma unroll
    for (int r = 0; r < 8; ++r) { acc1[r] = 0.f; acc2[r] = 0.f; }

#pragma unroll 2
    for (int k0 = 0; k0 < 128; k0 += 4) {
        float wr1[4], wr2[4];
#pragma unroll
        for (int kk = 0; kk < 4; ++kk) {
            wr1[kk] = w1[(k0 + kk) * 64 + col];
            wr2[kk] = w2[(k0 + kk) * 64 + col];
        }
#pragma unroll
        for (int r = 0; r < 8; ++r) {
            const float4 xv = *(const float4*)&xs[g * 8 + r][k0];
            acc1[r] += xv.x * wr1[0] + xv.y * wr1[1] + xv.z * wr1[2] + xv.w * wr1[3];
            acc2[r] += xv.x * wr2[0] + xv.y * wr2[1] + xv.z * wr2[2] + xv.w * wr2[3];
        }
    }

    const float bv1 = b1[col];
    const float bv2 = b2[col];
#pragma unroll
    for (int r = 0; r < 8; ++r) {
        const int gr = row0 + g * 8 + r;
        if (gr < NN) {
            const float v1 = acc1[r] + bv1;
            a[gr * 64 + col]    = v1;
            ab[gr * 64 + col]   = f2bf(v1);
            skip[gr * 64 + col] = acc2[r] + bv2;
        }
    }
}

// ---------------------------------------------------------------------------
// k_t: t[n,h] = a[n,:] @ u[:,h]   ([NN,64]@[64,4]) — one thread per (n,h)
// ---------------------------------------------------------------------------
__global__ __launch_bounds__(256) void k_t(
    const float* __restrict__ a, const float* __restrict__ u,
    float* __restrict__ t)
{
    const int gid = blockIdx.x * 256 + threadIdx.x;
    if (gid >= NN * 4) return;
    const int n = gid >> 2, h = gid & 3;
    const float* ar = a + n * 64;
    float s = 0.f;
#pragma unroll 4
    for (int k = 0; k < 64; ++k) s += ar[k] * u[k * 4 + h];
    t[gid] = s;
}

// ---------------------------------------------------------------------------
// k_lin3: out = h@W + b   ([NN,64]@[64,64])
// ---------------------------------------------------------------------------
__global__ __launch_bounds__(256) void k_lin3(
    const float* __restrict__ h,
    const float* __restrict__ w, const float* __restrict__ b,
    float* __restrict__ out)
{
    __shared__ float hs[32][64];
    const int tid = threadIdx.x;
    const int row0 = blockIdx.x * 32;
    for (int i = tid; i < 32 * 64; i += 256) {
        const int gr = row0 + (i >> 6);
        ((float*)hs)[i] = (gr < NN) ? h[gr * 64 + (i & 63)] : 0.f;
    }
    __syncthreads();

    const int col = tid & 63;
    const int g = tid >> 6;
    float acc[8];
#pragma unroll
    for (int r = 0; r < 8; ++r) acc[r] = 0.f;

#pragma unroll 2
    for (int k0 = 0; k0 < 64; k0 += 4) {
        float wr[4];
#pragma unroll
        for (int kk = 0; kk < 4; ++kk)
            wr[kk] = w[(k0 + kk) * 64 + col];
#pragma unroll
        for (int r = 0; r < 8; ++r) {
            const float4 xv = *(const float4*)&hs[g * 8 + r][k0];
            acc[r] += xv.x * wr[0] + xv.y * wr[1] + xv.z * wr[2] + xv.w * wr[3];
        }
    }

    const float bv = b[col];
#pragma unroll
    for (int r = 0; r < 8; ++r) {
        const int gr = row0 + g * 8 + r;
        if (gr < NN) out[gr * 64 + col] = acc[r] + bv;
    }
}

// ---------------------------------------------------------------------------
// CSR build: histogram -> hierarchical scan -> scatter (src only, 4B)
// ---------------------------------------------------------------------------
__global__ __launch_bounds__(256) void k_hist(const int* __restrict__ ei,
                                              int* __restrict__ deg)
{
    const int i = blockIdx.x * 256 + threadIdx.x;
    if (i < NE) atomicAdd(&deg[ei[NE + i]], 1);
}

__global__ __launch_bounds__(256) void k_blocksum(const int* __restrict__ deg,
                                                  int* __restrict__ bsum)
{
    __shared__ int red[256];
    const int t = threadIdx.x;
    const int i = blockIdx.x * 256 + t;
    red[t] = (i < NN) ? deg[i] : 0;
    __syncthreads();
    for (int off = 128; off > 0; off >>= 1) {
        if (t < off) red[t] += red[t + off];
        __syncthreads();
    }
    if (t == 0) bsum[blockIdx.x] = red[0];
}

__global__ __launch_bounds__(256) void k_scanb(int* __restrict__ bsum)
{
    __shared__ int s[256];
    const int t = threadIdx.x;
    s[t] = (t < NB) ? bsum[t] : 0;
    __syncthreads();
    for (int off = 1; off < 256; off <<= 1) {
        const int v = (t >= off) ? s[t - off] : 0;
        __syncthreads();
        s[t] += v;
        __syncthreads();
    }
    if (t < NB) bsum[t] = (t == 0) ? 0 : s[t - 1];
}

__global__ __launch_bounds__(256) void k_scanfin(const int* __restrict__ deg,
                                                 const int* __restrict__ bsum,
                                                 int* __restrict__ row_ptr,
                                                 int* __restrict__ fill)
{
    __shared__ int s[256];
    const int t = threadIdx.x;
    const int i = blockIdx.x * 256 + t;
    const int v = (i < NN) ? deg[i] : 0;
    s[t] = v;
    __syncthreads();
    for (int off = 1; off < 256; off <<= 1) {
        const int u = (t >= off) ? s[t - off] : 0;
        __syncthreads();
        s[t] += u;
        __syncthreads();
    }
    const int excl = s[t] - v + bsum[blockIdx.x];
    if (i < NN) { row_ptr[i] = excl; fill[i] = excl; }
    if (i == NN - 1) row_ptr[NN] = excl + v;
}

__global__ __launch_bounds__(256) void k_scatter(const int* __restrict__ ei,
                                                 int* __restrict__ fill,
                                                 int* __restrict__ ssrc)
{
    const int i = blockIdx.x * 256 + threadIdx.x;
    if (i >= NE) return;
    const int src = ei[i];
    const int dst = ei[NE + i];
    const int pos = atomicAdd(&fill[dst], 1);
    ssrc[pos] = src;
}

// ---------------------------------------------------------------------------
// k_conv: fused FeaStConv layer. Block = 32 nodes; wave g owns rows
// g*8..g*8+7.
//  Phase A (per wave, per row): aggregate z_h[f] = sum_e q_eh*a_bf16[src][f]
//    (softmax per 64-edge chunk computed lane-parallel, broadcast via shfl;
//    mean folded into q) -> z written to LDS as fp32 float4 (32KB tile).
//  Phase B: dense GEMM zcat[32,256] @ Wp[256,64] from LDS (wave-uniform
//    float4 broadcasts, zero unpacks) with fused bias+skip+relu epilogue,
//    emitting fp32 out + bf16 copy. No z HBM round-trip.
// ---------------------------------------------------------------------------
__global__ __launch_bounds__(256) void k_conv(
    const int* __restrict__ row_ptr, const int* __restrict__ ssrc,
    const float* __restrict__ t, const ushort16* __restrict__ ab,
    const float* __restrict__ c, const float* __restrict__ w,
    const float* __restrict__ bias, const float* __restrict__ skip,
    float* __restrict__ out, ushort16* __restrict__ outb)
{
    __shared__ float zs[32][256];   // 32 KB
    const int tid = threadIdx.x;
    const int lane = tid & 63;
    const int g = tid >> 6;
    const int row0 = blockIdx.x * 32;
    const float4 tc = *(const float4*)c;

    // ---- phase A: aggregation into LDS (wave-private rows) ----
    for (int rr = 0; rr < 8; ++rr) {
        const int r = g * 8 + rr;
        const int node = row0 + r;
        if (node >= NN) break;

        const int r0 = row_ptr[node];
        const int r1 = row_ptr[node + 1];
        const int deg = r1 - r0;
        const float invdeg = (deg > 0) ? 1.f / (float)deg : 0.f;
        const float4 td = ((const float4*)t)[node];

        float z0 = 0.f, z1 = 0.f, z2 = 0.f, z3 = 0.f;
        for (int base = r0; base < r1; base += 64) {
            const int m = min(64, r1 - base);

            int src = 0;
            float q0 = 0.f, q1 = 0.f, q2 = 0.f, q3 = 0.f;
            if (lane < m) {
                src = ssrc[base + lane];
                const float4 ts = ((const float4*)t)[src];
                const float l0 = ts.x - td.x + tc.x;
                const float l1 = ts.y - td.y + tc.y;
                const float l2 = ts.z - td.z + tc.z;
                const float l3 = ts.w - td.w + tc.w;
                const float mx = fmaxf(fmaxf(l0, l1), fmaxf(l2, l3));
                const float e0 = __expf(l0 - mx);
                const float e1 = __expf(l1 - mx);
                const float e2 = __expf(l2 - mx);
                const float e3 = __expf(l3 - mx);
                const float s = invdeg / (e0 + e1 + e2 + e3);
                q0 = e0 * s; q1 = e1 * s; q2 = e2 * s; q3 = e3 * s;
            }

            int e = 0;
            for (; e + 3 < m; e += 4) {
#pragma unroll
                for (int k = 0; k < 4; ++k) {
                    const int se = __shfl(src, e + k, 64);
                    const float a0 = __shfl(q0, e + k, 64);
                    const float a1 = __shfl(q1, e + k, 64);
                    const float a2 = __shfl(q2, e + k, 64);
                    const float a3 = __shfl(q3, e + k, 64);
                    const float av = bf2f(ab[se * 64 + lane]);
                    z0 += a0 * av; z1 += a1 * av; z2 += a2 * av; z3 += a3 * av;
                }
            }
            for (; e < m; ++e) {
                const int se = __shfl(src, e, 64);
                const float a0 = __shfl(q0, e, 64);
                const float a1 = __shfl(q1, e, 64);
                const float a2 = __shfl(q2, e, 64);
                const float a3 = __shfl(q3, e, 64);
                const float av = bf2f(ab[se * 64 + lane]);
                z0 += a0 * av; z1 += a1 * av; z2 += a2 * av; z3 += a3 * av;
            }
        }
        // zs[r][f*4+h] = z_h[f]; lane=f writes 4 consecutive floats
        *(float4*)&zs[r][lane * 4] = make_float4(z0, z1, z2, z3);
    }
    __syncthreads();

    // ---- phase B: GEMM zs[32,256] @ Wp[256,64] + epilogue ----
    const int col = lane;
    float acc[8];
#pragma unroll
    for (int r = 0; r < 8; ++r) acc[r] = 0.f;

    for (int k0 = 0; k0 < 256; k0 += 8) {
        float wr[8];
#pragma unroll
        for (int kk = 0; kk < 8; ++kk) {
            const int idx = k0 + kk;     // idx = f*4+h
            wr[kk] = w[(idx >> 2) * 256 + (idx & 3) * 64 + col];
        }
#pragma unroll
        for (int r = 0; r < 8; ++r) {
            const float4 za = *(const float4*)&zs[g * 8 + r][k0];     // broadcast
            const float4 zb = *(const float4*)&zs[g * 8 + r][k0 + 4];
            acc[r] += za.x * wr[0] + za.y * wr[1] + za.z * wr[2] + za.w * wr[3]
                    + zb.x * wr[4] + zb.y * wr[5] + zb.z * wr[6] + zb.w * wr[7];
        }
    }

    const float bv = bias[col];
#pragma unroll
    for (int r = 0; r < 8; ++r) {
        const int gr = row0 + g * 8 + r;
        if (gr < NN) {
            const float v = fmaxf(acc[r] + bv + skip[gr * 64 + col], 0.f);
            out[gr * 64 + col]  = v;
            outb[gr * 64 + col] = f2bf(v);
        }
    }
}

extern "C" void kernel_launch(void* const* d_in, const int* in_sizes, int n_in,
                              void* d_out, int out_size, void* d_ws, size_t ws_size,
                              hipStream_t stream) {
    const float* x       = (const float*)d_in[0];
    const int*   ei      = (const int*)d_in[1];   // [2, NE] int32
    const float* lin1_w  = (const float*)d_in[2];
    const float* lin1_b  = (const float*)d_in[3];
    const float* lin2_w  = (const float*)d_in[4];
    const float* lin2_b  = (const float*)d_in[5];
    const float* lin3_w  = (const float*)d_in[6];
    const float* lin3_b  = (const float*)d_in[7];
    const float* conv1_w = (const float*)d_in[8];
    const float* conv1_u = (const float*)d_in[9];
    const float* conv1_c = (const float*)d_in[10];
    const float* conv1_bias = (const float*)d_in[11];
    const float* conv2_w = (const float*)d_in[12];
    const float* conv2_u = (const float*)d_in[13];
    const float* conv2_c = (const float*)d_in[14];
    const float* conv2_bias = (const float*)d_in[15];
    float* out = (float*)d_out;

    // workspace layout (~44 MB, 16B-aligned sections)
    char* p = (char*)d_ws;
    float* a       = (float*)p;          p += (size_t)NN * 64 * 4;   // fp32 a / h
    float* skip    = (float*)p;          p += (size_t)NN * 64 * 4;
    float* tt      = (float*)p;          p += (size_t)NN * 4 * 4;
    ushort16* ab   = (ushort16*)p;       p += (size_t)NN * 64 * 2;   // bf16 a / h
    ushort16* obsc = (ushort16*)p;       p += (size_t)NN * 64 * 2;   // scratch outb (L2)
    int* ssrc      = (int*)p;            p += (size_t)NE * 4;
    int* deg       = (int*)p;            p += (size_t)NN * 4;
    int* row_ptr   = (int*)p;            p += (size_t)(NN + 1) * 4;
    int* fill      = (int*)p;            p += (size_t)NN * 4;
    int* bsum      = (int*)p;

    // ---- CSR build (edge_index identical for both layers) ----
    hipMemsetAsync(deg, 0, (size_t)NN * sizeof(int), stream);
    k_hist<<<(NE + 255) / 256, 256, 0, stream>>>(ei, deg);
    k_blocksum<<<NB, 256, 0, stream>>>(deg, bsum);
    k_scanb<<<1, 256, 0, stream>>>(bsum);
    k_scanfin<<<NB, 256, 0, stream>>>(deg, bsum, row_ptr, fill);
    k_scatter<<<(NE + 255) / 256, 256, 0, stream>>>(ei, fill, ssrc);

    // ---- layer 1 ----
    k_lin12<<<(NN + 31) / 32, 256, 0, stream>>>(x, lin1_w, lin1_b, lin2_w, lin2_b,
                                                a, ab, skip);
    k_t<<<(NN * 4 + 255) / 256, 256, 0, stream>>>(a, conv1_u, tt);
    k_conv<<<(NN + 31) / 32, 256, 0, stream>>>(row_ptr, ssrc, tt, ab, conv1_c,
                                               conv1_w, conv1_bias, skip, a, obsc);

    // ---- layer 2 ---- (h fp32 in a, bf16 in obsc)
    k_t<<<(NN * 4 + 255) / 256, 256, 0, stream>>>(a, conv2_u, tt);
    k_lin3<<<(NN + 31) / 32, 256, 0, stream>>>(a, lin3_w, lin3_b, skip);
    k_conv<<<(NN + 31) / 32, 256, 0, stream>>>(row_ptr, ssrc, tt, obsc, conv2_c,
                                               conv2_w, conv2_bias, skip, out, ab);
}